// Round 9
// baseline (38341.351 us; speedup 1.0000x reference)
//
#include <hip/hip_runtime.h>

#define V 32000
#define D 256
#define H 256
#define T 128
#define B 32
#define SOS 126
#define H2 512

#define NBLK 320
#define NTHR 256
#define SCOPE __HIP_MEMORY_SCOPE_AGENT
#define LDS_FLOATS 17408   // 16384 x-slab + 1024 scratch = 69632 B (2 blocks/CU)
#define S0 16384           // scratch base (floats)

typedef float f32x4 __attribute__((ext_vector_type(4)));

// wide agent-scope (L2-bypass, L3-coherent) ops for cross-block state only
#define AGLOAD(d, p) asm volatile("global_load_dwordx4 %0, %1, off sc0 sc1" : "=v"(d) : "v"(p))
#define AGSTORE(p, d) asm volatile("global_store_dwordx4 %0, %1, off sc0 sc1" :: "v"(p), "v"(d) : "memory")
#define AGWAIT1(a) asm volatile("s_waitcnt vmcnt(0)" : "+v"(a) :: "memory")
#define AGWAIT2(a,b) asm volatile("s_waitcnt vmcnt(0)" : "+v"(a),"+v"(b) :: "memory")
#define AGWAIT4(a,b,c,d) asm volatile("s_waitcnt vmcnt(0)" : "+v"(a),"+v"(b),"+v"(c),"+v"(d) :: "memory")
#define AGWAIT8(a,b,c,d,e,f,g,h) asm volatile("s_waitcnt vmcnt(0)" : "+v"(a),"+v"(b),"+v"(c),"+v"(d),"+v"(e),"+v"(f),"+v"(g),"+v"(h) :: "memory")
#define AGWAIT8P(a,b,c,d,e,f,g,h) asm volatile("s_waitcnt vmcnt(8)" : "+v"(a),"+v"(b),"+v"(c),"+v"(d),"+v"(e),"+v"(f),"+v"(g),"+v"(h) :: "memory")

__device__ __forceinline__ float sigf(float x) { return 1.f / (1.f + __expf(-x)); }
__device__ __forceinline__ float ftanh(float x) {
    x = fminf(15.f, fmaxf(-15.f, x));
    float e = __expf(2.f * x);
    return (e - 1.f) / (e + 1.f);
}

__device__ __forceinline__ float lda(const float* p) {
    return __hip_atomic_load(p, __ATOMIC_RELAXED, SCOPE);
}
__device__ __forceinline__ void sta(float* p, float v) {
    __hip_atomic_store(p, v, __ATOMIC_RELAXED, SCOPE);
}
__device__ __forceinline__ int ldai(const int* p) {
    return __hip_atomic_load(p, __ATOMIC_RELAXED, SCOPE);
}
__device__ __forceinline__ void stai(int* p, int v) {
    __hip_atomic_store(p, v, __ATOMIC_RELAXED, SCOPE);
}
__device__ __forceinline__ float rdlane(float v, int l) {
    return __int_as_float(__builtin_amdgcn_readlane(__float_as_int(v), l));
}

__device__ __forceinline__ void amerge(float& m, float& s, int& mi, float m2, float s2, int i2) {
    if (m2 > m)      { s = s2 + s * __expf(m - m2); m = m2; mi = i2; }
    else if (m > m2) { s = s + s2 * __expf(m2 - m); }
    else             { s = s + s2; mi = (mi < i2) ? mi : i2; }
}

// ---------------- grid barrier: active-set sweep + per-XCD gen replicas
__device__ __forceinline__ void gbar(int* __restrict__ slots, int* __restrict__ gen,
                                     int tgt, bool heavy, int nactive) {
    __syncthreads();
    if (threadIdx.x == 0 && ((int)blockIdx.x < nactive || blockIdx.x == 0)) {
        if (heavy) __builtin_amdgcn_fence(__ATOMIC_RELEASE, "agent");
        stai(slots + (size_t)blockIdx.x * 32, tgt);
    }
    if (blockIdx.x == 0) {
        for (int i = threadIdx.x; i < nactive; i += NTHR) {
            unsigned g1 = 0;
            while (ldai(slots + (size_t)i * 32) < tgt) {
                __builtin_amdgcn_s_sleep(1);
                if (++g1 > 100000000u) break;   // safety: garbage > hang
            }
        }
        asm volatile("" ::: "memory");
        __syncthreads();
        if (threadIdx.x < 8) stai(gen + threadIdx.x * 32, tgt);
    } else {
        if (threadIdx.x == 0) {
            const int* g = gen + (blockIdx.x & 7) * 32;
            unsigned gd = 0;
            while (ldai(g) < tgt) {
                __builtin_amdgcn_s_sleep(2);
                if (++gd > 100000000u) break;
            }
            asm volatile("" ::: "memory");
        }
    }
    if (heavy && threadIdx.x == 0) __builtin_amdgcn_fence(__ATOMIC_ACQUIRE, "agent");
    __syncthreads();
}

// ---------------- fp32 transpose (for WahT)
__global__ __launch_bounds__(256) void k_tr(const float* __restrict__ src,
                                            float* __restrict__ dst, int R, int C) {
    __shared__ float tle[32][33];
    int rb = blockIdx.x * 32, cb = blockIdx.y * 32;
    int lr = threadIdx.x & 31, lc = threadIdx.x >> 5;
#pragma unroll
    for (int i = 0; i < 32; i += 8) tle[lc + i][lr] = src[(size_t)(rb + lc + i) * C + cb + lr];
    __syncthreads();
#pragma unroll
    for (int i = 0; i < 32; i += 8) dst[(size_t)(cb + lc + i) * R + rb + lr] = tle[lr][lc + i];
}

// ---------------- bf16 transpose (Wout -> WoutB[k][row] ushort, RNE)
__global__ __launch_bounds__(256) void k_trb(const float* __restrict__ src,
                                             unsigned short* __restrict__ dst, int R, int C) {
    __shared__ float tle[32][33];
    int rb = blockIdx.x * 32, cb = blockIdx.y * 32;
    int lr = threadIdx.x & 31, lc = threadIdx.x >> 5;
#pragma unroll
    for (int i = 0; i < 32; i += 8) tle[lc + i][lr] = src[(size_t)(rb + lc + i) * C + cb + lr];
    __syncthreads();
#pragma unroll
    for (int i = 0; i < 32; i += 8) {
        unsigned u = __float_as_uint(tle[lr][lc + i]);
        unsigned r = (u + 0x7fffu + ((u >> 16) & 1u)) >> 16;
        dst[(size_t)(cb + lc + i) * R + rb + lr] = (unsigned short)r;
    }
}

// ---------------- WencT[k][dir*1024 + u*4+g]
__global__ __launch_bounds__(256) void k_prep_encw(
    const float* __restrict__ Wih_f, const float* __restrict__ Whh_f,
    const float* __restrict__ Wih_b, const float* __restrict__ Whh_b,
    float* __restrict__ WencT) {
    int idx = blockIdx.x * 256 + threadIdx.x;     // 512*2048
    int k = idx >> 11, col = idx & 2047;
    int dir = col >> 10, cu = col & 1023;
    int u = cu >> 2, g = cu & 3;
    const float* Wih = dir ? Wih_b : Wih_f;
    const float* Whh = dir ? Whh_b : Whh_f;
    float v = (k < 256) ? Wih[(g * H + u) * D + k] : Whh[(g * H + u) * H + (k - 256)];
    WencT[idx] = v;
}

// ---------------- WdT[k][u*4+g]
__global__ __launch_bounds__(256) void k_prep_decw(const float* __restrict__ Wih_d,
                                                   const float* __restrict__ Whh_d,
                                                   float* __restrict__ WdT) {
    int idx = blockIdx.x * 256 + threadIdx.x;     // 1280*2048
    int k = idx >> 11, col = idx & 2047;
    int u = col >> 2, g = col & 3;
    float v = (k < 768) ? Wih_d[(size_t)(g * H2 + u) * 768 + k]
                        : Whh_d[(size_t)(g * H2 + u) * H2 + (k - 768)];
    WdT[idx] = v;
}

// ---------------- final: out = logits - lse[b*T+t]
__global__ __launch_bounds__(256) void k_norm(float* __restrict__ out,
                                              const float* __restrict__ lse) {
    const int total4 = B * T * V / 4;
    int stride = gridDim.x * 256;
    for (int i4 = blockIdx.x * 256 + threadIdx.x; i4 < total4; i4 += stride) {
        int rowv = i4 / (V / 4);
        float l = lse[rowv];
        float4* p = (float4*)out + i4;
        float4 v = *p;
        v.x -= l; v.y -= l; v.z -= l; v.w -= l;
        *p = v;
    }
}

// ==================== THE PERSISTENT KERNEL ====================
__global__ __launch_bounds__(256, 2) void k_seq(
    const int* __restrict__ x, const float* __restrict__ emb_enc,
    const float* __restrict__ emb_dec,
    const float* __restrict__ bih_f, const float* __restrict__ bhh_f,
    const float* __restrict__ bih_b, const float* __restrict__ bhh_b,
    const float* __restrict__ bih_d, const float* __restrict__ bhh_d,
    const float* __restrict__ Wa_e, const float* __restrict__ Wa_h,
    const float* __restrict__ b_a, const float* __restrict__ v_a,
    const float* __restrict__ bout,
    const float* __restrict__ WencT, const float* __restrict__ WdT,
    const unsigned short* __restrict__ WoutB, const float* __restrict__ WahT,
    float* __restrict__ enc_out, float* __restrict__ proj_e,
    float* __restrict__ zpenc,
    float* __restrict__ hdecT, float* __restrict__ cdecT,
    float* __restrict__ xcatT, float* __restrict__ q_buf, float* __restrict__ zp_h,
    float* __restrict__ P4, float* __restrict__ lse, float* __restrict__ out,
    int* slots, int* gen) {
    extern __shared__ float xs[];
    const int blk = blockIdx.x, tid = threadIdx.x;
    const int kc = (tid >> 3) & 7;
    const int rp = (tid >> 6) * 8 + (tid & 7);   // 0..31 across block
    const int lane = tid & 63;
    const int ks = tid >> 6;                     // wave id 0..3 (k-split)
    int bgen = 0;
    float c_priv[16];

    // ===================== ENCODER (R8 structure) =====================
    for (int t = 0; t <= T; ++t) {
        if (blk < 128) {
            int rowgrp = blk >> 2, c = (blk >> 1) & 1, bh = blk & 1;
            int dir = rowgrp >> 4;
            if (c == 0) {
                if (t < T) {
                    for (int i = tid; i < 4096; i += 256) {
                        int bb = i >> 8, k = i & 255;
                        int tok = x[(bh * 16 + bb) * T + t];
                        xs[k * 16 + (((bb & 12) ^ ((k & 3) << 2)) | (bb & 3))] =
                            emb_enc[tok * 256 + k];
                    }
                }
            } else {
                if (t == 0) {
#pragma unroll
                    for (int j = 0; j < 16; ++j) {
                        xs[tid + j * 256] = 0.f;
                        c_priv[j] = 0.f;
                    }
                } else {
                    bool writer = (rowgrp & 15) == 0;
                    const float* zpp = zpenc + ((t - 1) & 1) * 131072;
#pragma unroll
                    for (int j = 0; j < 16; ++j) {
                        int i = tid + j * 256;
                        int u = i >> 4, bb = i & 15, bG = bh * 16 + bb;
                        int r = dir * 1024 + u * 4;
                        float z[4];
#pragma unroll
                        for (int g = 0; g < 4; ++g) {
                            float bias = (dir ? bih_b : bih_f)[g * 256 + u] +
                                         (dir ? bhh_b : bhh_f)[g * 256 + u];
                            z[g] = lda(zpp + (size_t)(r + g) * 32 + bG) +
                                   lda(zpp + (size_t)(2048 + r + g) * 32 + bG) + bias;
                        }
                        float cp = c_priv[j];
                        float c2 = sigf(z[1]) * cp + sigf(z[0]) * ftanh(z[2]);
                        float h2 = sigf(z[3]) * ftanh(c2);
                        c_priv[j] = c2;
                        xs[u * 16 + (((bb & 12) ^ ((u & 3) << 2)) | (bb & 3))] = h2;
                        if (writer) {
                            enc_out[(size_t)(bG * T + (t - 1)) * H2 + dir * 256 + u] = h2;
                            if (t == T) {
                                hdecT[(dir * 256 + u) * 32 + bG] = h2;
                                cdecT[(dir * 256 + u) * 32 + bG] = c2;
                            }
                        }
                    }
                }
            }
            __syncthreads();
            if (t < T) {
                int r0 = rowgrp * 64 + rp * 2;
                float a0[16], a1[16];
#pragma unroll
                for (int j = 0; j < 16; ++j) { a0[j] = 0.f; a1[j] = 0.f; }
#pragma unroll 4
                for (int j = 0; j < 32; ++j) {
                    int kl = kc + 8 * j;
                    float2 w = *(const float2*)(WencT + (size_t)(c * 256 + kl) * 2048 + r0);
                    const float* xp = xs + kl * 16;
                    int sw = (kl & 3) << 2;
#pragma unroll
                    for (int q = 0; q < 4; ++q) {
                        f32x4 xv = *(const f32x4*)(xp + ((q * 4) ^ sw));
                        a0[q*4+0] = fmaf(w.x, xv.x, a0[q*4+0]); a1[q*4+0] = fmaf(w.y, xv.x, a1[q*4+0]);
                        a0[q*4+1] = fmaf(w.x, xv.y, a0[q*4+1]); a1[q*4+1] = fmaf(w.y, xv.y, a1[q*4+1]);
                        a0[q*4+2] = fmaf(w.x, xv.z, a0[q*4+2]); a1[q*4+2] = fmaf(w.y, xv.z, a1[q*4+2]);
                        a0[q*4+3] = fmaf(w.x, xv.w, a0[q*4+3]); a1[q*4+3] = fmaf(w.y, xv.w, a1[q*4+3]);
                    }
                }
#pragma unroll
                for (int j = 0; j < 16; ++j) {
                    a0[j] += __shfl_xor(a0[j], 8); a0[j] += __shfl_xor(a0[j], 16); a0[j] += __shfl_xor(a0[j], 32);
                    a1[j] += __shfl_xor(a1[j], 8); a1[j] += __shfl_xor(a1[j], 16); a1[j] += __shfl_xor(a1[j], 32);
                }
                if (((tid >> 3) & 7) == 0) {
                    float* zb = zpenc + (t & 1) * 131072 + (size_t)(c * 2048 + r0) * 32 + bh * 16;
                    f32x4 s0 = {a0[0],a0[1],a0[2],a0[3]}, s1 = {a0[4],a0[5],a0[6],a0[7]};
                    f32x4 s2 = {a0[8],a0[9],a0[10],a0[11]}, s3 = {a0[12],a0[13],a0[14],a0[15]};
                    AGSTORE(zb, s0); AGSTORE(zb + 4, s1); AGSTORE(zb + 8, s2); AGSTORE(zb + 12, s3);
                    f32x4 t0 = {a1[0],a1[1],a1[2],a1[3]}, t1 = {a1[4],a1[5],a1[6],a1[7]};
                    f32x4 t2 = {a1[8],a1[9],a1[10],a1[11]}, t3 = {a1[12],a1[13],a1[14],a1[15]};
                    AGSTORE(zb + 32, t0); AGSTORE(zb + 36, t1); AGSTORE(zb + 40, t2); AGSTORE(zb + 44, t3);
                }
            }
        }
        ++bgen; gbar(slots, gen, bgen, t == T, 128);
    }

    // ===================== pre-decoder: proj_e + q0 =====================
    {
        if (blk < 256) {
            int r0 = blk * 16;
            for (int i = tid; i < 16 * 512; i += 256) {
                int r = i >> 9, k = i & 511;
                xs[r * 512 + k] = enc_out[(size_t)(r0 + r) * H2 + k];
            }
            __syncthreads();
            int j0 = tid * 2;
            float acc0[16], acc1[16];
#pragma unroll
            for (int r = 0; r < 16; ++r) { acc0[r] = 0.f; acc1[r] = 0.f; }
            const float* w0 = Wa_e + j0 * H2;
            const float* w1 = Wa_e + (j0 + 1) * H2;
            for (int k = 0; k < H2; k += 4) {
                float4 wa = *(const float4*)(w0 + k);
                float4 wb = *(const float4*)(w1 + k);
#pragma unroll
                for (int r = 0; r < 16; ++r) {
                    float4 xv = *(const float4*)(&xs[r * 512 + k]);
                    acc0[r] = fmaf(wa.x, xv.x, acc0[r]); acc0[r] = fmaf(wa.y, xv.y, acc0[r]);
                    acc0[r] = fmaf(wa.z, xv.z, acc0[r]); acc0[r] = fmaf(wa.w, xv.w, acc0[r]);
                    acc1[r] = fmaf(wb.x, xv.x, acc1[r]); acc1[r] = fmaf(wb.y, xv.y, acc1[r]);
                    acc1[r] = fmaf(wb.z, xv.z, acc1[r]); acc1[r] = fmaf(wb.w, xv.w, acc1[r]);
                }
            }
#pragma unroll
            for (int r = 0; r < 16; ++r) {
                float2 st; st.x = acc0[r]; st.y = acc1[r];
                *(float2*)(proj_e + (size_t)(r0 + r) * H2 + j0) = st;
            }
        } else {
            int gi = (blk - 256) * 256 + tid;
            int j = gi >> 5, b = gi & 31;
            float a0 = 0, a1 = 0, a2 = 0, a3 = 0;
            const float* wr = Wa_h + (size_t)j * H2;
            for (int k = 0; k < H2; k += 4) {
                float4 w = *(const float4*)(wr + k);
                a0 = fmaf(w.x, hdecT[(k    ) * 32 + b], a0);
                a1 = fmaf(w.y, hdecT[(k + 1) * 32 + b], a1);
                a2 = fmaf(w.z, hdecT[(k + 2) * 32 + b], a2);
                a3 = fmaf(w.w, hdecT[(k + 3) * 32 + b], a3);
            }
            q_buf[b * H2 + j] = (a0 + a1) + (a2 + a3);
        }
    }
    ++bgen; gbar(slots, gen, bgen, true, 320);

    // ===================== DECODER =====================
    for (int t = 0; t < T; ++t) {
        // ---------- phA: attention chain (0..31) || Whh x h_{t-1} (32..63)
        if (blk < 32) {
            int b = blk;
            int tok = SOS;
            if (t > 0) {
                float* rm = xs + S0; float* rs = rm + 256; int* ri = (int*)(rs + 256);
                float m = -INFINITY, s = 0.f; int mi = 0x7fffffff;
                if (tid < 250) {
                    f32x4 v0;
                    AGLOAD(v0, P4 + ((size_t)b * 256 + tid) * 4);
                    AGWAIT1(v0);
                    amerge(m, s, mi, v0.x, v0.y, __float_as_int(v0.z));
                }
                rm[tid] = m; rs[tid] = s; ri[tid] = mi;
                __syncthreads();
                for (int off = 128; off >= 1; off >>= 1) {
                    if (tid < off) {
                        float m1 = rm[tid], m2 = rm[tid + off];
                        float s1 = rs[tid], s2 = rs[tid + off];
                        int i1 = ri[tid], i2 = ri[tid + off];
                        float m_, s_; int i_;
                        if (m2 > m1)      { m_ = m2; s_ = s2 + s1 * __expf(m1 - m2); i_ = i2; }
                        else if (m1 > m2) { m_ = m1; s_ = s1 + s2 * __expf(m2 - m1); i_ = i1; }
                        else              { m_ = m1; s_ = s1 + s2; i_ = (i1 < i2) ? i1 : i2; }
                        rm[tid] = m_; rs[tid] = s_; ri[tid] = i_;
                    }
                    __syncthreads();
                }
                if (tid == 0) lse[b * T + (t - 1)] = rm[0] + logf(rs[0]);
                __syncthreads();
                tok = ri[0];
                __syncthreads();
            }
            // embedding -> xcatT[k][b]
            sta(xcatT + tid * 32 + b, emb_dec[tok * 256 + tid]);
            // energy -> es (LDS); proj_e cached
            float* es = xs + S0;
            {
                int l = tid & 63, wv = tid >> 6;
                const float* qp = q_buf + (size_t)b * H2 + l * 8;
                f32x4 q0, q1;
                AGLOAD(q0, qp); AGLOAD(q1, qp + 4);
                AGWAIT2(q0, q1);
                f32x4 ba0 = *(const f32x4*)(b_a + l * 8);
                f32x4 ba1 = *(const f32x4*)(b_a + l * 8 + 4);
                f32x4 va0 = *(const f32x4*)(v_a + l * 8);
                f32x4 va1 = *(const f32x4*)(v_a + l * 8 + 4);
                q0 += ba0; q1 += ba1;
#pragma unroll 4
                for (int tti = 0; tti < 32; ++tti) {
                    int tt = wv * 32 + tti;
                    const float* pp = proj_e + ((size_t)(b * T) + tt) * H2 + l * 8;
                    f32x4 p0 = *(const f32x4*)(pp);
                    f32x4 p1 = *(const f32x4*)(pp + 4);
                    float s = ftanh(p0.x + q0.x) * va0.x + ftanh(p0.y + q0.y) * va0.y
                            + ftanh(p0.z + q0.z) * va0.z + ftanh(p0.w + q0.w) * va0.w
                            + ftanh(p1.x + q1.x) * va1.x + ftanh(p1.y + q1.y) * va1.y
                            + ftanh(p1.z + q1.z) * va1.z + ftanh(p1.w + q1.w) * va1.w;
#pragma unroll
                    for (int off = 32; off >= 1; off >>= 1) s += __shfl_xor(s, off);
                    if (l == 0) es[tt] = s;
                }
            }
            __syncthreads();
            float* red = xs + S0 + 128; float* wsm = xs + S0 + 256;
            if (tid < 128) red[tid] = es[tid];
            __syncthreads();
            for (int off = 64; off >= 1; off >>= 1) {
                if (tid < off) red[tid] = fmaxf(red[tid], red[tid + off]);
                __syncthreads();
            }
            float M = red[0];
            __syncthreads();
            float ev = 0.f;
            if (tid < 128) { ev = __expf(es[tid] - M); red[tid] = ev; }
            __syncthreads();
            for (int off = 64; off >= 1; off >>= 1) {
                if (tid < off) red[tid] += red[tid + off];
                __syncthreads();
            }
            float S = red[0];
            __syncthreads();
            if (tid < 128) wsm[tid] = ev / S;
            __syncthreads();
            float acc0 = 0.f, acc1 = 0.f;
            const float* eo = enc_out + (size_t)b * T * H2;
#pragma unroll 8
            for (int t2 = 0; t2 < T; ++t2) {
                float wv2 = wsm[t2];
                acc0 = fmaf(wv2, eo[t2 * H2 + tid], acc0);
                acc1 = fmaf(wv2, eo[t2 * H2 + tid + 256], acc1);
            }
            sta(xcatT + (256 + tid) * 32 + b, acc0);
            sta(xcatT + (512 + tid) * 32 + b, acc1);
        } else if (blk < 64) {
            // Whh_d x h: 32 blocks x 64 cols; lane=col, 4-wave k-split(128)
            int col0 = (blk - 32) * 64;
            {   // stage h [512][32] fp32 -> xs linear
                f32x4 v[16];
#pragma unroll
                for (int j = 0; j < 16; ++j)
                    AGLOAD(v[j], hdecT + (size_t)(tid + j * 256) * 4);
                AGWAIT8P(v[0], v[1], v[2], v[3], v[4], v[5], v[6], v[7]);
#pragma unroll
                for (int j = 0; j < 8; ++j) *(f32x4*)(xs + (size_t)(tid + j * 256) * 4) = v[j];
                AGWAIT8(v[8], v[9], v[10], v[11], v[12], v[13], v[14], v[15]);
#pragma unroll
                for (int j = 8; j < 16; ++j) *(f32x4*)(xs + (size_t)(tid + j * 256) * 4) = v[j];
            }
            __syncthreads();
            float acc[32];
#pragma unroll
            for (int b = 0; b < 32; ++b) acc[b] = 0.f;
            int col = col0 + lane;
#pragma unroll 2
            for (int kk = 0; kk < 128; ++kk) {
                int k = ks * 128 + kk;
                float w = WdT[(size_t)(768 + k) * 2048 + col];
                float vx = xs[k * 32 + (tid & 31)];
#pragma unroll
                for (int b = 0; b < 32; ++b) acc[b] = fmaf(w, rdlane(vx, b), acc[b]);
            }
            __syncthreads();
#pragma unroll
            for (int b = 0; b < 32; b += 4) {
                f32x4 st = {acc[b], acc[b+1], acc[b+2], acc[b+3]};
                *(f32x4*)(xs + ((size_t)(ks * 64 + lane) * 32 + b)) = st;
            }
            __syncthreads();
            for (int i4 = tid; i4 < 512; i4 += 256) {
                int cl = i4 >> 3, b4 = (i4 & 7) * 4;
                f32x4 s = *(const f32x4*)(xs + ((size_t)cl * 32 + b4));
                s += *(const f32x4*)(xs + ((size_t)(64 + cl) * 32 + b4));
                s += *(const f32x4*)(xs + ((size_t)(128 + cl) * 32 + b4));
                s += *(const f32x4*)(xs + ((size_t)(192 + cl) * 32 + b4));
                AGSTORE(zp_h + (size_t)(col0 + cl) * 32 + b4, s);
            }
        }
        ++bgen; gbar(slots, gen, bgen, false, 64);

        // ---------- phB: Wih x xcat + fused cell (blocks 0..31)
        if (blk < 32) {
            int col0 = blk * 64;
            int col = col0 + lane;
            float acc[32];
#pragma unroll
            for (int b = 0; b < 32; ++b) acc[b] = 0.f;
#pragma unroll
            for (int half = 0; half < 2; ++half) {
                {   // stage xcatT[half*384 .. +384) -> xs linear [384][32]
                    f32x4 v[12];
#pragma unroll
                    for (int j = 0; j < 12; ++j)
                        AGLOAD(v[j], xcatT + (size_t)half * 12288 + (size_t)(tid + j * 256) * 4);
                    AGWAIT8(v[0], v[1], v[2], v[3], v[4], v[5], v[6], v[7]);
#pragma unroll
                    for (int j = 0; j < 8; ++j) *(f32x4*)(xs + (size_t)(tid + j * 256) * 4) = v[j];
                    AGWAIT4(v[8], v[9], v[10], v[11]);
#pragma unroll
                    for (int j = 8; j < 12; ++j) *(f32x4*)(xs + (size_t)(tid + j * 256) * 4) = v[j];
                }
                __syncthreads();
#pragma unroll 2
                for (int kk = 0; kk < 96; ++kk) {
                    int kl = ks * 96 + kk;
                    int k = half * 384 + kl;
                    float w = WdT[(size_t)k * 2048 + col];
                    float vx = xs[kl * 32 + (tid & 31)];
#pragma unroll
                    for (int b = 0; b < 32; ++b) acc[b] = fmaf(w, rdlane(vx, b), acc[b]);
                }
                __syncthreads();
            }
#pragma unroll
            for (int b = 0; b < 32; b += 4) {
                f32x4 st = {acc[b], acc[b+1], acc[b+2], acc[b+3]};
                *(f32x4*)(xs + ((size_t)(ks * 64 + lane) * 32 + b)) = st;
            }
            __syncthreads();
            // reduce -> zsum at xs+8192
            for (int i4 = tid; i4 < 512; i4 += 256) {
                int cl = i4 >> 3, b4 = (i4 & 7) * 4;
                f32x4 s = *(const f32x4*)(xs + ((size_t)cl * 32 + b4));
                s += *(const f32x4*)(xs + ((size_t)(64 + cl) * 32 + b4));
                s += *(const f32x4*)(xs + ((size_t)(128 + cl) * 32 + b4));
                s += *(const f32x4*)(xs + ((size_t)(192 + cl) * 32 + b4));
                *(f32x4*)(xs + 8192 + (size_t)cl * 32 + b4) = s;
            }
            __syncthreads();
            // fused cell: 16 units x 32 b
            for (int i = tid; i < 512; i += 256) {
                int ul = i >> 5, b = i & 31;
                int u = blk * 16 + ul;
                float z[4];
#pragma unroll
                for (int g = 0; g < 4; ++g)
                    z[g] = xs[8192 + (size_t)(ul * 4 + g) * 32 + b]
                         + lda(zp_h + (size_t)(u * 4 + g) * 32 + b)
                         + bih_d[g * H2 + u] + bhh_d[g * H2 + u];
                float cp = cdecT[u * 32 + b];     // block-private across steps
                float c2 = sigf(z[1]) * cp + sigf(z[0]) * ftanh(z[2]);
                cdecT[u * 32 + b] = c2;
                sta(hdecT + u * 32 + b, sigf(z[3]) * ftanh(c2));
            }
        }
        ++bgen; gbar(slots, gen, bgen, false, 32);

        // ---------- phC: logits bf16 (0..249) + q fp32 (250..257)
        if (blk < 258) {
            {   // stage h [512][32] fp32 -> xs linear
                f32x4 v[16];
#pragma unroll
                for (int j = 0; j < 16; ++j)
                    AGLOAD(v[j], hdecT + (size_t)(tid + j * 256) * 4);
                AGWAIT8P(v[0], v[1], v[2], v[3], v[4], v[5], v[6], v[7]);
#pragma unroll
                for (int j = 0; j < 8; ++j) *(f32x4*)(xs + (size_t)(tid + j * 256) * 4) = v[j];
                AGWAIT8(v[8], v[9], v[10], v[11], v[12], v[13], v[14], v[15]);
#pragma unroll
                for (int j = 8; j < 16; ++j) *(f32x4*)(xs + (size_t)(tid + j * 256) * 4) = v[j];
            }
            __syncthreads();
            if (blk < 250) {
                int col0 = blk * 128;
                int cp = lane * 2;
                float a0[32], a1[32];
#pragma unroll
                for (int b = 0; b < 32; ++b) { a0[b] = 0.f; a1[b] = 0.f; }
#pragma unroll 2
                for (int kk = 0; kk < 128; ++kk) {
                    int k = ks * 128 + kk;
                    unsigned uw = *(const unsigned*)(WoutB + (size_t)k * V + col0 + cp);
                    float wx = __uint_as_float(uw << 16);
                    float wy = __uint_as_float(uw & 0xffff0000u);
                    float vx = xs[k * 32 + (tid & 31)];
#pragma unroll
                    for (int b = 0; b < 32; ++b) {
                        float sx = rdlane(vx, b);
                        a0[b] = fmaf(wx, sx, a0[b]);
                        a1[b] = fmaf(wy, sx, a1[b]);
                    }
                }
                __syncthreads();
#pragma unroll
                for (int b = 0; b < 32; b += 4) {
                    f32x4 s0 = {a0[b], a0[b+1], a0[b+2], a0[b+3]};
                    f32x4 s1 = {a1[b], a1[b+1], a1[b+2], a1[b+3]};
                    *(f32x4*)(xs + ((size_t)(ks * 128 + cp) * 32 + b)) = s0;
                    *(f32x4*)(xs + ((size_t)(ks * 128 + cp + 1) * 32 + b)) = s1;
                }
                __syncthreads();
                // epilogue: thread = (colgrp of 16, b): sum ks + bias, store, argmax
                float* pm8 = xs + S0; float* ps8 = pm8 + 256; int* pi8 = (int*)(ps8 + 256);
                {
                    int tcol = tid & 7, b = tid >> 3;
                    float m = -INFINITY, s = 0.f; int mi = 0;
#pragma unroll
                    for (int e = 0; e < 16; ++e) {
                        int cl = tcol * 16 + e;
                        float v = xs[(size_t)cl * 32 + b]
                                + xs[(size_t)(128 + cl) * 32 + b]
                                + xs[(size_t)(256 + cl) * 32 + b]
                                + xs[(size_t)(384 + cl) * 32 + b]
                                + bout[col0 + cl];
                        __builtin_nontemporal_store(v, out + ((size_t)(b * T) + t) * V + col0 + cl);
                        if (v > m) { s *= __expf(m - v); m = v; mi = col0 + cl; }
                        s += __expf(v - m);
                    }
                    pm8[tcol * 32 + b] = m; ps8[tcol * 32 + b] = s; pi8[tcol * 32 + b] = mi;
                }
                __syncthreads();
                if (tid < 32) {
                    int b = tid;
                    float m = pm8[b], s = ps8[b]; int mi = pi8[b];
#pragma unroll
                    for (int g = 1; g < 8; ++g)
                        amerge(m, s, mi, pm8[g * 32 + b], ps8[g * 32 + b], pi8[g * 32 + b]);
                    f32x4 pk; pk.x = m; pk.y = s; pk.z = __int_as_float(mi); pk.w = 0.f;
                    AGSTORE(P4 + ((size_t)b * 256 + blk) * 4, pk);
                }
            } else {
                // q: 8 blocks x 64 cols fp32
                int col0 = (blk - 250) * 64;
                int col = col0 + lane;
                float acc[32];
#pragma unroll
                for (int b = 0; b < 32; ++b) acc[b] = 0.f;
#pragma unroll 2
                for (int kk = 0; kk < 128; ++kk) {
                    int k = ks * 128 + kk;
                    float w = WahT[(size_t)k * H2 + col];
                    float vx = xs[k * 32 + (tid & 31)];
#pragma unroll
                    for (int b = 0; b < 32; ++b) acc[b] = fmaf(w, rdlane(vx, b), acc[b]);
                }
                __syncthreads();
#pragma unroll
                for (int b = 0; b < 32; b += 4) {
                    f32x4 st = {acc[b], acc[b+1], acc[b+2], acc[b+3]};
                    *(f32x4*)(xs + ((size_t)(ks * 64 + lane) * 32 + b)) = st;
                }
                __syncthreads();
                for (int i = tid; i < 2048; i += 256) {
                    int cl = i >> 5, b = i & 31;
                    float s = xs[(size_t)cl * 32 + b] + xs[(size_t)(64 + cl) * 32 + b]
                            + xs[(size_t)(128 + cl) * 32 + b] + xs[(size_t)(192 + cl) * 32 + b];
                    sta(q_buf + (size_t)b * H2 + col0 + cl, s);
                }
            }
        }
        ++bgen; gbar(slots, gen, bgen, false, 258);
    }

    // ---------- tail: lse for t = 127
    if (blk < 32) {
        int b = blk;
        float* rm = xs + S0; float* rs = rm + 256;
        float m = -INFINITY, s = 0.f; int mi = 0;
        if (tid < 250) {
            f32x4 v0;
            AGLOAD(v0, P4 + ((size_t)b * 256 + tid) * 4);
            AGWAIT1(v0);
            amerge(m, s, mi, v0.x, v0.y, __float_as_int(v0.z));
        }
        rm[tid] = m; rs[tid] = s;
        __syncthreads();
        for (int off = 128; off >= 1; off >>= 1) {
            if (tid < off) {
                float m1 = rm[tid], m2 = rm[tid + off];
                float s1 = rs[tid], s2 = rs[tid + off];
                float m_, s_;
                if (m2 > m1)      { m_ = m2; s_ = s2 + s1 * __expf(m1 - m2); }
                else if (m1 > m2) { m_ = m1; s_ = s1 + s2 * __expf(m2 - m1); }
                else              { m_ = m1; s_ = s1 + s2; }
                rm[tid] = m_; rs[tid] = s_;
            }
            __syncthreads();
        }
        if (tid == 0) lse[b * T + (T - 1)] = rm[0] + logf(rs[0]);
    }
}

extern "C" void kernel_launch(void* const* d_in, const int* in_sizes, int n_in,
                              void* d_out, int out_size, void* d_ws, size_t ws_size,
                              hipStream_t stream) {
    const int* x          = (const int*)d_in[0];
    const float* emb_enc  = (const float*)d_in[1];
    const float* Wih_f    = (const float*)d_in[2];
    const float* Whh_f    = (const float*)d_in[3];
    const float* bih_f    = (const float*)d_in[4];
    const float* bhh_f    = (const float*)d_in[5];
    const float* Wih_b    = (const float*)d_in[6];
    const float* Whh_b    = (const float*)d_in[7];
    const float* bih_b    = (const float*)d_in[8];
    const float* bhh_b    = (const float*)d_in[9];
    const float* emb_dec  = (const float*)d_in[10];
    const float* Wa_h     = (const float*)d_in[11];
    const float* Wa_e     = (const float*)d_in[12];
    const float* v_a      = (const float*)d_in[13];
    const float* b_a      = (const float*)d_in[14];
    const float* Wih_d    = (const float*)d_in[15];
    const float* Whh_d    = (const float*)d_in[16];
    const float* bih_d    = (const float*)d_in[17];
    const float* bhh_d    = (const float*)d_in[18];
    const float* Wout     = (const float*)d_in[19];
    const float* bout     = (const float*)d_in[20];
    float* out = (float*)d_out;

    float* ws = (float*)d_ws;
    size_t o = 0;
    float* enc_out = ws + o; o += (size_t)B * T * H2;       // 2,097,152
    float* proj_e  = ws + o; o += (size_t)B * T * H2;       // 2,097,152
    unsigned short* WoutB = (unsigned short*)(ws + o); o += (size_t)H2 * V / 2;  // 8,192,000 floats
    float* WdT     = ws + o; o += (size_t)1280 * 2048;      // 2,621,440
    float* WencT   = ws + o; o += (size_t)512 * 2048;       // 1,048,576
    float* WahT    = ws + o; o += (size_t)H2 * H2;          // 262,144
    float* zpenc   = ws + o; o += 2 * 2 * 2048 * 32;        // 262,144
    float* hdecT   = ws + o; o += 16384;
    float* cdecT   = ws + o; o += 16384;
    float* xcatT   = ws + o; o += 768 * 32;                 // 24,576  [k][b]
    float* q_buf   = ws + o; o += 16384;
    float* zp_h    = ws + o; o += 2048 * 32;                // 65,536
    float* P4      = ws + o; o += (size_t)32 * 256 * 4;     // 32,768
    float* lse     = ws + o; o += 32 * 128;
    int*   slots   = (int*)(ws + o); o += 320 * 32;
    int*   gen     = (int*)(ws + o); o += 8 * 32;

    hipMemsetAsync(slots, 0, (320 * 32 + 8 * 32) * sizeof(int), stream);

    k_trb<<<dim3(1000, 16), 256, 0, stream>>>(Wout, WoutB, V, H2);
    k_tr<<<dim3(16, 16), 256, 0, stream>>>(Wa_h, WahT, H2, H2);
    k_prep_encw<<<4096, 256, 0, stream>>>(Wih_f, Whh_f, Wih_b, Whh_b, WencT);
    k_prep_decw<<<10240, 256, 0, stream>>>(Wih_d, Whh_d, WdT);

    k_seq<<<NBLK, NTHR, LDS_FLOATS * sizeof(float), stream>>>(
        x, emb_enc, emb_dec,
        bih_f, bhh_f, bih_b, bhh_b, bih_d, bhh_d,
        Wa_e, Wa_h, b_a, v_a, bout,
        WencT, WdT, WoutB, WahT,
        enc_out, proj_e, zpenc,
        hdecT, cdecT, xcatT, q_buf, zp_h,
        P4, lse, out, slots, gen);

    k_norm<<<4096, 256, 0, stream>>>(out, lse);
}